// Round 2
// baseline (392.578 us; speedup 1.0000x reference)
//
#include <hip/hip_runtime.h>
#include <cstdint>
#include <cstddef>

// Problem constants (fixed by the reference)
static constexpr int kQ = 300;
static constexpr int kL2 = 21760;

// ---------------------------------------------------------------------------
// GEMM: C[M,256] = A[M,256] @ W[256,256]^T + bias[256], optional row zero-mask.
// 64x64 block tile, BK=32, 256 threads, 4x4 per-thread tile. M-guarded.
// ---------------------------------------------------------------------------
__global__ __launch_bounds__(256)
void gemm_nt_bias(const float* __restrict__ A, const float* __restrict__ W,
                  const float* __restrict__ bias, float* __restrict__ C,
                  int M, const unsigned char* __restrict__ rowmask)
{
    __shared__ float As[32][68];   // [k][m], stride 68 floats (16B-aligned rows)
    __shared__ float Ws[32][68];   // [k][n]
    const int tid = threadIdx.x;
    const int m0 = blockIdx.x * 64;
    const int n0 = blockIdx.y * 64;
    const int tx = tid & 15, ty = tid >> 4;
    float acc[4][4] = {};

    for (int k0 = 0; k0 < 256; k0 += 32) {
#pragma unroll
        for (int i = 0; i < 2; i++) {
            int t = tid + i * 256;
            int r = t >> 3;             // 0..63
            int c4 = (t & 7) << 2;      // 0,4,...,28
            int ra = min(m0 + r, M - 1);
            float4 va = *(const float4*)(A + (size_t)ra * 256 + k0 + c4);
            As[c4 + 0][r] = va.x; As[c4 + 1][r] = va.y;
            As[c4 + 2][r] = va.z; As[c4 + 3][r] = va.w;
            float4 vw = *(const float4*)(W + (size_t)(n0 + r) * 256 + k0 + c4);
            Ws[c4 + 0][r] = vw.x; Ws[c4 + 1][r] = vw.y;
            Ws[c4 + 2][r] = vw.z; Ws[c4 + 3][r] = vw.w;
        }
        __syncthreads();
#pragma unroll
        for (int kk = 0; kk < 32; kk++) {
            float4 a = *(const float4*)&As[kk][ty * 4];
            float4 w = *(const float4*)&Ws[kk][tx * 4];
            float av[4] = {a.x, a.y, a.z, a.w};
            float wv[4] = {w.x, w.y, w.z, w.w};
#pragma unroll
            for (int i = 0; i < 4; i++)
#pragma unroll
                for (int j = 0; j < 4; j++)
                    acc[i][j] += av[i] * wv[j];
        }
        __syncthreads();
    }

#pragma unroll
    for (int i = 0; i < 4; i++) {
        int r = m0 + ty * 4 + i;
        if (r >= M) continue;
        float z = (rowmask && rowmask[r]) ? 0.f : 1.f;
        int n = n0 + tx * 4;
        float4 o;
        o.x = (acc[i][0] + bias[n + 0]) * z;
        o.y = (acc[i][1] + bias[n + 1]) * z;
        o.z = (acc[i][2] + bias[n + 2]) * z;
        o.w = (acc[i][3] + bias[n + 3]) * z;
        *(float4*)(C + (size_t)r * 256 + n) = o;
    }
}

// ---------------------------------------------------------------------------
// Per-(b,q) fused kernel: aw/ob GEMV + softmaxes + bilinear sampling.
// 512 threads: thread = (k in 0..63, ch in 0..7); each thread owns float4 chunk
// ch of the 32-dim head vector, for all 8 heads.
// MODE 0: weight taps by level softmax, write mask_pre[(bq*64+k)*256 + h*32 + ch*4]
// MODE 1: weight taps by spatial softmax (E/(16S)), reduce over k in-block,
//         write out_pre[bq*256 + ...]
// ---------------------------------------------------------------------------
template<int MODE>
__global__ __launch_bounds__(512)
void sample_kernel(const float* __restrict__ query,
                   const float* __restrict__ val,      // (B*L2, 256) projected value
                   const float* __restrict__ Wattn, const float* __restrict__ battn,
                   const float* __restrict__ Wbox,  const float* __restrict__ bbox,
                   const float* __restrict__ ref_windows,
                   const float* __restrict__ vvr,      // (B, NL, 2)
                   float* __restrict__ outp)           // mask_pre or out_pre
{
    __shared__ float qrow[256];
    __shared__ float awob[256];        // [0:128) aw, [128:256) ob
    __shared__ float wgt[8][4][4];     // [h][l][qd]: level (MODE 0) or spatial (MODE 1)
    __shared__ float4 box[8][4];       // [h][l] = {cx*vrx, cy*vry, relu(sx)*vrx, relu(sy)*vry}
    __shared__ float oacc[256];        // MODE 1 reduction buffer

    const int bq = blockIdx.x;
    const int b = bq / kQ;
    const int tid = threadIdx.x;

    if (tid < 64)
        ((float4*)qrow)[tid] = ((const float4*)(query + (size_t)bq * 256))[tid];
    __syncthreads();

    if (tid < 256) {
        const float* Wrow = (tid < 128) ? (Wattn + (size_t)tid * 256)
                                        : (Wbox + (size_t)(tid - 128) * 256);
        float s = (tid < 128) ? battn[tid] : bbox[tid - 128];
#pragma unroll 8
        for (int d4 = 0; d4 < 64; d4++) {
            float4 w = ((const float4*)Wrow)[d4];
            float4 qv = ((const float4*)qrow)[d4];
            s += w.x * qv.x + w.y * qv.y + w.z * qv.z + w.w * qv.w;
        }
        awob[tid] = s;
    }
    __syncthreads();

    if (tid < 8) {
        const int h = tid;
        float m = -1e30f;
        float E[16];
#pragma unroll
        for (int i = 0; i < 16; i++) m = fmaxf(m, awob[h * 16 + i]);
        float S = 0.f;
#pragma unroll
        for (int i = 0; i < 16; i++) { E[i] = expf(awob[h * 16 + i] - m); S += E[i]; }
        if (MODE == 0) {
#pragma unroll
            for (int qd = 0; qd < 4; qd++) {
                float Sq = E[qd] + E[4 + qd] + E[8 + qd] + E[12 + qd];
                float inv = 1.f / Sq;
#pragma unroll
                for (int l = 0; l < 4; l++) wgt[h][l][qd] = E[l * 4 + qd] * inv;
            }
        } else {
            float inv = 1.f / (16.f * S);
#pragma unroll
            for (int l = 0; l < 4; l++)
#pragma unroll
                for (int qd = 0; qd < 4; qd++) wgt[h][l][qd] = E[l * 4 + qd] * inv;
        }
    }
    if (tid >= 64 && tid < 96) {
        const int t = tid - 64;
        const int h = t >> 2, l = t & 3;
        float4 rw = ((const float4*)ref_windows)[bq];
        float ob0 = awob[128 + h * 16 + l * 4 + 0];
        float ob1 = awob[128 + h * 16 + l * 4 + 1];
        float ob2 = awob[128 + h * 16 + l * 4 + 2];
        float ob3 = awob[128 + h * 16 + l * 4 + 3];
        float cx = rw.x + ob0 * 0.125f * rw.z;
        float cy = rw.y + ob1 * 0.125f * rw.w;
        float sx = fmaxf(rw.z + ob2 * 0.125f * rw.z, 0.f);
        float sy = fmaxf(rw.w + ob3 * 0.125f * rw.w, 0.f);
        float vrx = vvr[(b * 4 + l) * 2 + 0];
        float vry = vvr[(b * 4 + l) * 2 + 1];
        box[h][l] = make_float4(cx * vrx, cy * vry, sx * vrx, sy * vry);
    }
    if (MODE == 1 && tid < 64) {
        float4 z = make_float4(0.f, 0.f, 0.f, 0.f);
        ((float4*)oacc)[tid] = z;
    }
    __syncthreads();

    const int k = tid >> 3;       // sample point 0..63
    const int ch = tid & 7;       // float4 chunk of 32-dim head vec
    const float kx = (float)(k & 7) * 0.125f - 0.4375f;   // (j - 3.5)/8
    const float ky = (float)(k >> 3) * 0.125f - 0.4375f;  // (i - 3.5)/8
    const int qd = (((k >> 5) & 1) << 1) | ((k >> 2) & 1);

    float4 acc[8];
#pragma unroll
    for (int h = 0; h < 8; h++) acc[h] = make_float4(0.f, 0.f, 0.f, 0.f);

    static constexpr int LW[4]  = {128, 64, 32, 16};
    static constexpr int LST[4] = {0, 16384, 20480, 21504};

#pragma unroll
    for (int l = 0; l < 4; l++) {
        const int Wl = LW[l];     // square levels: H == W
        const float* vbase = val + ((size_t)(b * kL2 + LST[l]) * 256) + ch * 4;
#pragma unroll 2
        for (int h = 0; h < 8; h++) {
            float4 bx = box[h][l];
            float lw = wgt[h][l][qd];
            float x = (bx.x + kx * bx.z) * Wl - 0.5f;
            float y = (bx.y + ky * bx.w) * Wl - 0.5f;
            float x0f = floorf(x), y0f = floorf(y);
            float dx = x - x0f, dy = y - y0f;
            int x0 = (int)x0f, y0 = (int)y0f;
            int x1 = x0 + 1, y1 = y0 + 1;
            int x0c = min(max(x0, 0), Wl - 1), x1c = min(max(x1, 0), Wl - 1);
            int y0c = min(max(y0, 0), Wl - 1), y1c = min(max(y1, 0), Wl - 1);
            float vx0 = (x0 >= 0 && x0 < Wl) ? 1.f : 0.f;
            float vx1 = (x1 >= 0 && x1 < Wl) ? 1.f : 0.f;
            float vy0 = (y0 >= 0 && y0 < Wl) ? 1.f : 0.f;
            float vy1 = (y1 >= 0 && y1 < Wl) ? 1.f : 0.f;
            float wx0 = (1.f - dx), wx1 = dx, wy0 = (1.f - dy), wy1 = dy;
            float w00 = wx0 * wy0 * vx0 * vy0 * lw;
            float w10 = wx1 * wy0 * vx1 * vy0 * lw;
            float w01 = wx0 * wy1 * vx0 * vy1 * lw;
            float w11 = wx1 * wy1 * vx1 * vy1 * lw;
            const float* p00 = vbase + (size_t)(y0c * Wl + x0c) * 256 + h * 32;
            const float* p10 = vbase + (size_t)(y0c * Wl + x1c) * 256 + h * 32;
            const float* p01 = vbase + (size_t)(y1c * Wl + x0c) * 256 + h * 32;
            const float* p11 = vbase + (size_t)(y1c * Wl + x1c) * 256 + h * 32;
            float4 v00 = *(const float4*)p00;
            float4 v10 = *(const float4*)p10;
            float4 v01 = *(const float4*)p01;
            float4 v11 = *(const float4*)p11;
            acc[h].x += w00 * v00.x + w10 * v10.x + w01 * v01.x + w11 * v11.x;
            acc[h].y += w00 * v00.y + w10 * v10.y + w01 * v01.y + w11 * v11.y;
            acc[h].z += w00 * v00.z + w10 * v10.z + w01 * v01.z + w11 * v11.z;
            acc[h].w += w00 * v00.w + w10 * v10.w + w01 * v01.w + w11 * v11.w;
        }
    }

    if (MODE == 0) {
        float* mrow = outp + ((size_t)bq * 64 + k) * 256 + ch * 4;
#pragma unroll
        for (int h = 0; h < 8; h++)
            *(float4*)(mrow + h * 32) = acc[h];
    } else {
        // reduce over the 8 k's within each wave (lanes sharing ch = lane&7),
        // then LDS-atomic across the 8 waves.
        const int lane = tid & 63;
#pragma unroll
        for (int h = 0; h < 8; h++) {
            float4 v = acc[h];
#pragma unroll
            for (int mask = 8; mask <= 32; mask <<= 1) {
                v.x += __shfl_xor(v.x, mask);
                v.y += __shfl_xor(v.y, mask);
                v.z += __shfl_xor(v.z, mask);
                v.w += __shfl_xor(v.w, mask);
            }
            if (lane < 8) {
                int base = h * 32 + lane * 4;
                atomicAdd(&oacc[base + 0], v.x);
                atomicAdd(&oacc[base + 1], v.y);
                atomicAdd(&oacc[base + 2], v.z);
                atomicAdd(&oacc[base + 3], v.w);
            }
        }
        __syncthreads();
        if (tid < 64)
            ((float4*)(outp + (size_t)bq * 256))[tid] = ((float4*)oacc)[tid];
    }
}

// ---------------------------------------------------------------------------
extern "C" void kernel_launch(void* const* d_in, const int* in_sizes, int n_in,
                              void* d_out, int out_size, void* d_ws, size_t ws_size,
                              hipStream_t stream)
{
    const float* query       = (const float*)d_in[0];
    const float* value       = (const float*)d_in[1];
    const unsigned char* v_mask = (const unsigned char*)d_in[3];
    const float* vvr         = (const float*)d_in[5];
    const float* ref_windows = (const float*)d_in[6];
    const float* Wv    = (const float*)d_in[7];
    const float* bv    = (const float*)d_in[8];
    const float* Wbox  = (const float*)d_in[9];
    const float* bbox  = (const float*)d_in[10];
    const float* Wattn = (const float*)d_in[11];
    const float* battn = (const float*)d_in[12];
    const float* Wout  = (const float*)d_in[13];
    const float* bout  = (const float*)d_in[14];

    // workspace layout (all 16B aligned)
    float* val      = (float*)d_ws;                       // 43520*256 f32
    float* out_pre  = val + (size_t)43520 * 256;          // 600*256 f32
    float* mask_pre = out_pre + (size_t)640 * 256;        // 38400*256 f32

    float* out  = (float*)d_out;                          // 600*256
    float* mask = out + (size_t)600 * 256;                // 38400*256

    // 1) value projection: val = value @ Wv^T + bv, masked rows -> 0
    gemm_nt_bias<<<dim3(680, 4), 256, 0, stream>>>(value, Wv, bv, val, 43520, v_mask);
    // 2) level-weighted sampling -> mask_pre
    sample_kernel<0><<<600, 512, 0, stream>>>(query, val, Wattn, battn, Wbox, bbox,
                                              ref_windows, vvr, mask_pre);
    // 3) spatial-weighted sampling, k-reduced -> out_pre
    sample_kernel<1><<<600, 512, 0, stream>>>(query, val, Wattn, battn, Wbox, bbox,
                                              ref_windows, vvr, out_pre);
    // 4) mask = mask_pre @ Wout^T + bout
    gemm_nt_bias<<<dim3(600, 4), 256, 0, stream>>>(mask_pre, Wout, bout, mask, 38400, nullptr);
    // 5) out = out_pre @ Wout^T + bout
    gemm_nt_bias<<<dim3(10, 4), 256, 0, stream>>>(out_pre, Wout, bout, out, 600, nullptr);
}

// Round 3
// 285.703 us; speedup vs baseline: 1.3741x; 1.3741x over previous
//
#include <hip/hip_runtime.h>
#include <cstdint>
#include <cstddef>

// Problem constants (fixed by the reference)
static constexpr int kQ = 300;
static constexpr int kL2 = 21760;

// ---------------------------------------------------------------------------
// GEMM: C[M,256] = A[M,256] @ W[256,256]^T + bias[256], optional row zero-mask.
// 64x64 block tile, BK=32, 256 threads, 4x4 per-thread tile. M-guarded.
// ---------------------------------------------------------------------------
__global__ __launch_bounds__(256)
void gemm_nt_bias(const float* __restrict__ A, const float* __restrict__ W,
                  const float* __restrict__ bias, float* __restrict__ C,
                  int M, const unsigned char* __restrict__ rowmask)
{
    __shared__ float As[32][68];   // [k][m], stride 68 floats (16B-aligned rows)
    __shared__ float Ws[32][68];   // [k][n]
    const int tid = threadIdx.x;
    const int m0 = blockIdx.x * 64;
    const int n0 = blockIdx.y * 64;
    const int tx = tid & 15, ty = tid >> 4;
    float acc[4][4] = {};

    for (int k0 = 0; k0 < 256; k0 += 32) {
#pragma unroll
        for (int i = 0; i < 2; i++) {
            int t = tid + i * 256;
            int r = t >> 3;             // 0..63
            int c4 = (t & 7) << 2;      // 0,4,...,28
            int ra = min(m0 + r, M - 1);
            float4 va = *(const float4*)(A + (size_t)ra * 256 + k0 + c4);
            As[c4 + 0][r] = va.x; As[c4 + 1][r] = va.y;
            As[c4 + 2][r] = va.z; As[c4 + 3][r] = va.w;
            float4 vw = *(const float4*)(W + (size_t)(n0 + r) * 256 + k0 + c4);
            Ws[c4 + 0][r] = vw.x; Ws[c4 + 1][r] = vw.y;
            Ws[c4 + 2][r] = vw.z; Ws[c4 + 3][r] = vw.w;
        }
        __syncthreads();
#pragma unroll
        for (int kk = 0; kk < 32; kk++) {
            float4 a = *(const float4*)&As[kk][ty * 4];
            float4 w = *(const float4*)&Ws[kk][tx * 4];
            float av[4] = {a.x, a.y, a.z, a.w};
            float wv[4] = {w.x, w.y, w.z, w.w};
#pragma unroll
            for (int i = 0; i < 4; i++)
#pragma unroll
                for (int j = 0; j < 4; j++)
                    acc[i][j] += av[i] * wv[j];
        }
        __syncthreads();
    }

#pragma unroll
    for (int i = 0; i < 4; i++) {
        int r = m0 + ty * 4 + i;
        if (r >= M) continue;
        float z = (rowmask && rowmask[r]) ? 0.f : 1.f;
        int n = n0 + tx * 4;
        float4 o;
        o.x = (acc[i][0] + bias[n + 0]) * z;
        o.y = (acc[i][1] + bias[n + 1]) * z;
        o.z = (acc[i][2] + bias[n + 2]) * z;
        o.w = (acc[i][3] + bias[n + 3]) * z;
        *(float4*)(C + (size_t)r * 256 + n) = o;
    }
}

// ---------------------------------------------------------------------------
// Fused per-(b,q,khalf) kernel: aw/ob GEMV + softmaxes + bilinear sampling.
// Grid 1200 = (bq, khalf); 256 threads: thread = (klocal 0..31, ch 0..7).
// Produces: mask_pre rows (level-weighted), and per-block spatial partial
// out_part[block][256] = sum over its 32 k's of c[h][qd(k)] * acc  (exact
// factorization: spatial_w = level_w * c pointwise).
// ---------------------------------------------------------------------------
__global__ __launch_bounds__(256)
void sample_fused(const float* __restrict__ query,
                  const float* __restrict__ val,      // (B*L2, 256) projected value
                  const float* __restrict__ Wattn, const float* __restrict__ battn,
                  const float* __restrict__ Wbox,  const float* __restrict__ bbox,
                  const float* __restrict__ ref_windows,
                  const float* __restrict__ vvr,      // (B, NL, 2)
                  float* __restrict__ mask_pre,       // (B*Q*64, 256)
                  float* __restrict__ out_part)       // (1200, 256)
{
    __shared__ float qrow[256];
    __shared__ float awob[256];        // [0:128) aw, [128:256) ob
    __shared__ float wgt[8][4][4];     // [h][l][qd] level softmax
    __shared__ float cqd_s[8][4];      // [h][qd] = S_qd/(16*S)
    __shared__ float4 box[8][4];       // [h][l] = {cx*vrx, cy*vry, relu(sx)*vrx, relu(sy)*vry}
    __shared__ float warr[4][256];     // per-wave spatial partials

    const int blk = blockIdx.x;
    const int bq = blk >> 1;
    const int khalf = blk & 1;
    const int b = bq / kQ;
    const int tid = threadIdx.x;

    if (tid < 64)
        ((float4*)qrow)[tid] = ((const float4*)(query + (size_t)bq * 256))[tid];
    __syncthreads();

    {
        const float* Wrow = (tid < 128) ? (Wattn + (size_t)tid * 256)
                                        : (Wbox + (size_t)(tid - 128) * 256);
        float s = (tid < 128) ? battn[tid] : bbox[tid - 128];
#pragma unroll 8
        for (int d4 = 0; d4 < 64; d4++) {
            float4 w = ((const float4*)Wrow)[d4];
            float4 qv = ((const float4*)qrow)[d4];
            s += w.x * qv.x + w.y * qv.y + w.z * qv.z + w.w * qv.w;
        }
        awob[tid] = s;
    }
    __syncthreads();

    if (tid < 8) {
        const int h = tid;
        float m = -1e30f;
        float E[16];
#pragma unroll
        for (int i = 0; i < 16; i++) m = fmaxf(m, awob[h * 16 + i]);
        float S = 0.f;
#pragma unroll
        for (int i = 0; i < 16; i++) { E[i] = expf(awob[h * 16 + i] - m); S += E[i]; }
        float invS16 = 1.f / (16.f * S);
#pragma unroll
        for (int qd = 0; qd < 4; qd++) {
            float Sq = E[qd] + E[4 + qd] + E[8 + qd] + E[12 + qd];
            float inv = 1.f / Sq;
#pragma unroll
            for (int l = 0; l < 4; l++) wgt[h][l][qd] = E[l * 4 + qd] * inv;
            cqd_s[h][qd] = Sq * invS16;
        }
    }
    if (tid >= 64 && tid < 96) {
        const int t = tid - 64;
        const int h = t >> 2, l = t & 3;
        float4 rw = ((const float4*)ref_windows)[bq];
        float ob0 = awob[128 + h * 16 + l * 4 + 0];
        float ob1 = awob[128 + h * 16 + l * 4 + 1];
        float ob2 = awob[128 + h * 16 + l * 4 + 2];
        float ob3 = awob[128 + h * 16 + l * 4 + 3];
        float cx = rw.x + ob0 * 0.125f * rw.z;
        float cy = rw.y + ob1 * 0.125f * rw.w;
        float sx = fmaxf(rw.z + ob2 * 0.125f * rw.z, 0.f);
        float sy = fmaxf(rw.w + ob3 * 0.125f * rw.w, 0.f);
        float vrx = vvr[(b * 4 + l) * 2 + 0];
        float vry = vvr[(b * 4 + l) * 2 + 1];
        box[h][l] = make_float4(cx * vrx, cy * vry, sx * vrx, sy * vry);
    }
    __syncthreads();

    const int klocal = tid >> 3;            // 0..31
    const int k = khalf * 32 + klocal;      // sample point 0..63
    const int ch = tid & 7;                 // float4 chunk of 32-dim head vec
    const float kx = (float)(k & 7) * 0.125f - 0.4375f;   // (j - 3.5)/8
    const float ky = (float)(k >> 3) * 0.125f - 0.4375f;  // (i - 3.5)/8
    const int qd = (((k >> 5) & 1) << 1) | ((k >> 2) & 1);

    float4 acc[8];
#pragma unroll
    for (int h = 0; h < 8; h++) acc[h] = make_float4(0.f, 0.f, 0.f, 0.f);

    static constexpr int LW[4]  = {128, 64, 32, 16};
    static constexpr int LST[4] = {0, 16384, 20480, 21504};

#pragma unroll
    for (int l = 0; l < 4; l++) {
        const int Wl = LW[l];     // square levels: H == W
        const float* vbase = val + ((size_t)(b * kL2 + LST[l]) * 256) + ch * 4;
#pragma unroll 2
        for (int h = 0; h < 8; h++) {
            float4 bx = box[h][l];
            float lw = wgt[h][l][qd];
            float x = (bx.x + kx * bx.z) * Wl - 0.5f;
            float y = (bx.y + ky * bx.w) * Wl - 0.5f;
            float x0f = floorf(x), y0f = floorf(y);
            float dx = x - x0f, dy = y - y0f;
            int x0 = (int)x0f, y0 = (int)y0f;
            int x1 = x0 + 1, y1 = y0 + 1;
            int x0c = min(max(x0, 0), Wl - 1), x1c = min(max(x1, 0), Wl - 1);
            int y0c = min(max(y0, 0), Wl - 1), y1c = min(max(y1, 0), Wl - 1);
            float vx0 = (x0 >= 0 && x0 < Wl) ? 1.f : 0.f;
            float vx1 = (x1 >= 0 && x1 < Wl) ? 1.f : 0.f;
            float vy0 = (y0 >= 0 && y0 < Wl) ? 1.f : 0.f;
            float vy1 = (y1 >= 0 && y1 < Wl) ? 1.f : 0.f;
            float wx0 = (1.f - dx), wx1 = dx, wy0 = (1.f - dy), wy1 = dy;
            float w00 = wx0 * wy0 * vx0 * vy0 * lw;
            float w10 = wx1 * wy0 * vx1 * vy0 * lw;
            float w01 = wx0 * wy1 * vx0 * vy1 * lw;
            float w11 = wx1 * wy1 * vx1 * vy1 * lw;
            const float* p00 = vbase + (size_t)(y0c * Wl + x0c) * 256 + h * 32;
            const float* p10 = vbase + (size_t)(y0c * Wl + x1c) * 256 + h * 32;
            const float* p01 = vbase + (size_t)(y1c * Wl + x0c) * 256 + h * 32;
            const float* p11 = vbase + (size_t)(y1c * Wl + x1c) * 256 + h * 32;
            float4 v00 = *(const float4*)p00;
            float4 v10 = *(const float4*)p10;
            float4 v01 = *(const float4*)p01;
            float4 v11 = *(const float4*)p11;
            acc[h].x += w00 * v00.x + w10 * v10.x + w01 * v01.x + w11 * v11.x;
            acc[h].y += w00 * v00.y + w10 * v10.y + w01 * v01.y + w11 * v11.y;
            acc[h].z += w00 * v00.z + w10 * v10.z + w01 * v01.z + w11 * v11.z;
            acc[h].w += w00 * v00.w + w10 * v10.w + w01 * v01.w + w11 * v11.w;
        }
    }

    // mask_pre rows (level-weighted)
    float* mrow = mask_pre + ((size_t)bq * 64 + k) * 256 + ch * 4;
#pragma unroll
    for (int h = 0; h < 8; h++)
        *(float4*)(mrow + h * 32) = acc[h];

    // spatial partial: v = c[h][qd(k)] * acc, reduced over the block's 32 k's
    const int wave = tid >> 6;
    const int lane = tid & 63;
#pragma unroll
    for (int h = 0; h < 8; h++) {
        float c = cqd_s[h][qd];
        float4 v = make_float4(acc[h].x * c, acc[h].y * c, acc[h].z * c, acc[h].w * c);
#pragma unroll
        for (int m = 8; m <= 32; m <<= 1) {
            v.x += __shfl_xor(v.x, m);
            v.y += __shfl_xor(v.y, m);
            v.z += __shfl_xor(v.z, m);
            v.w += __shfl_xor(v.w, m);
        }
        if (lane < 8)
            ((float4*)&warr[wave][h * 32])[lane] = v;
    }
    __syncthreads();
    {
        float s = warr[0][tid] + warr[1][tid] + warr[2][tid] + warr[3][tid];
        out_part[(size_t)blk * 256 + tid] = s;
    }
}

// out_pre[bq] = out_part[2*bq] + out_part[2*bq+1]  (deterministic combine)
__global__ __launch_bounds__(256)
void combine_kernel(const float* __restrict__ out_part, float* __restrict__ out_pre)
{
    const int bq = blockIdx.x;
    const int d = threadIdx.x;
    out_pre[(size_t)bq * 256 + d] = out_part[(size_t)(2 * bq) * 256 + d]
                                  + out_part[(size_t)(2 * bq + 1) * 256 + d];
}

// ---------------------------------------------------------------------------
extern "C" void kernel_launch(void* const* d_in, const int* in_sizes, int n_in,
                              void* d_out, int out_size, void* d_ws, size_t ws_size,
                              hipStream_t stream)
{
    const float* query       = (const float*)d_in[0];
    const float* value       = (const float*)d_in[1];
    const unsigned char* v_mask = (const unsigned char*)d_in[3];
    const float* vvr         = (const float*)d_in[5];
    const float* ref_windows = (const float*)d_in[6];
    const float* Wv    = (const float*)d_in[7];
    const float* bv    = (const float*)d_in[8];
    const float* Wbox  = (const float*)d_in[9];
    const float* bbox  = (const float*)d_in[10];
    const float* Wattn = (const float*)d_in[11];
    const float* battn = (const float*)d_in[12];
    const float* Wout  = (const float*)d_in[13];
    const float* bout  = (const float*)d_in[14];

    // workspace layout (all 16B aligned)
    float* val      = (float*)d_ws;                       // 43520*256 f32
    float* out_part = val + (size_t)43520 * 256;          // 1200*256 f32
    float* out_pre  = out_part + (size_t)1200 * 256;      // 640*256 f32 (600 used)
    float* mask_pre = out_pre + (size_t)640 * 256;        // 38400*256 f32

    float* out  = (float*)d_out;                          // 600*256
    float* mask = out + (size_t)600 * 256;                // 38400*256

    // 1) value projection: val = value @ Wv^T + bv, masked rows -> 0
    gemm_nt_bias<<<dim3(680, 4), 256, 0, stream>>>(value, Wv, bv, val, 43520, v_mask);
    // 2) fused sampling: mask_pre (level-weighted) + per-block spatial partials
    sample_fused<<<1200, 256, 0, stream>>>(query, val, Wattn, battn, Wbox, bbox,
                                           ref_windows, vvr, mask_pre, out_part);
    // 3) combine spatial partials -> out_pre
    combine_kernel<<<600, 256, 0, stream>>>(out_part, out_pre);
    // 4) mask = mask_pre @ Wout^T + bout
    gemm_nt_bias<<<dim3(600, 4), 256, 0, stream>>>(mask_pre, Wout, bout, mask, 38400, nullptr);
    // 5) out = out_pre @ Wout^T + bout
    gemm_nt_bias<<<dim3(10, 4), 256, 0, stream>>>(out_pre, Wout, bout, out, 600, nullptr);
}

// Round 4
// 180.270 us; speedup vs baseline: 2.1777x; 1.5849x over previous
//
#include <hip/hip_runtime.h>
#include <cstdint>
#include <cstddef>

typedef unsigned short u16;
typedef unsigned int   u32;
typedef __attribute__((ext_vector_type(8))) short bf16x8;
typedef __attribute__((ext_vector_type(4))) float f32x4;

static constexpr int kQ = 300;
static constexpr int kL2 = 21760;

__device__ __forceinline__ u16 bf16_rne(float f) {
    u32 u = __float_as_uint(f);
    u += 0x7FFFu + ((u >> 16) & 1u);
    return (u16)(u >> 16);
}
__device__ __forceinline__ u32 pack2(float lo, float hi) {
    return (u32)bf16_rne(lo) | ((u32)bf16_rne(hi) << 16);
}
__device__ __forceinline__ float lo16(u32 u) { return __uint_as_float(u << 16); }
__device__ __forceinline__ float hi16(u32 u) { return __uint_as_float(u & 0xFFFF0000u); }

// ---------------------------------------------------------------------------
// f32 -> bf16 (RNE), n divisible by 8
// ---------------------------------------------------------------------------
__global__ __launch_bounds__(256)
void f32_to_bf16(const float* __restrict__ src, u16* __restrict__ dst, int n)
{
    int i = (blockIdx.x * 256 + threadIdx.x) * 8;
    if (i >= n) return;
    float4 a = *(const float4*)(src + i);
    float4 b = *(const float4*)(src + i + 4);
    uint4 o;
    o.x = pack2(a.x, a.y); o.y = pack2(a.z, a.w);
    o.z = pack2(b.x, b.y); o.w = pack2(b.z, b.w);
    *(uint4*)(dst + i) = o;
}

// ---------------------------------------------------------------------------
// MFMA bf16 GEMM: C[M,256] = A[M,256] @ W[256,256]^T + bias, opt rowmask.
// BM=BN=128, BK=32, 256 threads (4 waves, 2x2), wave tile 64x64 (4x4 frags).
// M must be divisible by 128. OUT_BF16: LDS-bounce epilogue, bf16 output.
// LDS chunk layout: chunk ci = g*128 + row  (g = k-octet 0..3), 16B chunks.
// MFMA 16x16x32 fragment: lane l holds row/col (l&15), k = (l>>4)*8 + e.
// ---------------------------------------------------------------------------
template<bool OUT_BF16>
__global__ __launch_bounds__(256)
void gemm_bf16(const u16* __restrict__ A, const u16* __restrict__ W,
               const float* __restrict__ bias, void* __restrict__ Cout,
               const unsigned char* __restrict__ rowmask)
{
    __shared__ u16 S[8192];            // 16KB: As=S[0:4096), Bs=S[4096:8192)
    u16* As = S;
    u16* Bs = S + 4096;
    const int tid = threadIdx.x;
    const int m0 = blockIdx.x * 128;
    const int n0 = blockIdx.y * 128;
    const int lane = tid & 63;
    const int w = tid >> 6;
    const int wm = w & 1, wn = w >> 1;
    const int g = lane >> 4, r = lane & 15;

    f32x4 acc[4][4];
#pragma unroll
    for (int i = 0; i < 4; i++)
#pragma unroll
        for (int j = 0; j < 4; j++)
            acc[i][j] = (f32x4){0.f, 0.f, 0.f, 0.f};

    for (int kt = 0; kt < 8; ++kt) {
        const int k0 = kt * 32;
#pragma unroll
        for (int i = 0; i < 2; ++i) {
            int c = tid + i * 256;          // 0..511
            int m = c >> 2, gg = c & 3;
            uint4 va = *(const uint4*)(A + (size_t)(m0 + m) * 256 + k0 + gg * 8);
            *(uint4*)(As + ((gg * 128 + m) << 3)) = va;
            uint4 vb = *(const uint4*)(W + (size_t)(n0 + m) * 256 + k0 + gg * 8);
            *(uint4*)(Bs + ((gg * 128 + m) << 3)) = vb;
        }
        __syncthreads();
        bf16x8 af[4], bf[4];
#pragma unroll
        for (int mf = 0; mf < 4; ++mf)
            af[mf] = *(const bf16x8*)(As + ((g * 128 + wm * 64 + mf * 16 + r) << 3));
#pragma unroll
        for (int nf = 0; nf < 4; ++nf)
            bf[nf] = *(const bf16x8*)(Bs + ((g * 128 + wn * 64 + nf * 16 + r) << 3));
#pragma unroll
        for (int mf = 0; mf < 4; ++mf)
#pragma unroll
            for (int nf = 0; nf < 4; ++nf)
                acc[mf][nf] = __builtin_amdgcn_mfma_f32_16x16x32_bf16(
                    af[mf], bf[nf], acc[mf][nf], 0, 0, 0);
        __syncthreads();
    }

    if (!OUT_BF16) {
        float* C = (float*)Cout;
#pragma unroll
        for (int nf = 0; nf < 4; ++nf) {
            int ng = n0 + wn * 64 + nf * 16 + r;
            float bb = bias[ng];
#pragma unroll
            for (int mf = 0; mf < 4; ++mf) {
                int mg = m0 + wm * 64 + mf * 16 + g * 4;
#pragma unroll
                for (int reg = 0; reg < 4; ++reg) {
                    float z = 1.f;
                    if (rowmask && rowmask[mg + reg]) z = 0.f;
                    C[(size_t)(mg + reg) * 256 + ng] = (acc[mf][nf][reg] + bb) * z;
                }
            }
        }
    } else {
        u16* C = (u16*)Cout;
#pragma unroll
        for (int round = 0; round < 2; ++round) {
            __syncthreads();
            if (wn == round) {
#pragma unroll
                for (int nf = 0; nf < 4; ++nf) {
                    int col = nf * 16 + r;
                    float bb = bias[n0 + round * 64 + col];
#pragma unroll
                    for (int mf = 0; mf < 4; ++mf) {
                        int row0 = wm * 64 + mf * 16 + g * 4;
#pragma unroll
                        for (int reg = 0; reg < 4; ++reg) {
                            float z = 1.f;
                            if (rowmask && rowmask[m0 + row0 + reg]) z = 0.f;
                            S[(row0 + reg) * 64 + col] =
                                bf16_rne((acc[mf][nf][reg] + bb) * z);
                        }
                    }
                }
            }
            __syncthreads();
            int row = tid >> 1, hb = tid & 1;
            const u16* src = S + row * 64 + hb * 32;
            u16* dst = C + (size_t)(m0 + row) * 256 + n0 + round * 64 + hb * 32;
#pragma unroll
            for (int j = 0; j < 4; ++j)
                ((uint4*)dst)[j] = ((const uint4*)src)[j];
        }
    }
}

// ---------------------------------------------------------------------------
// f32 GEMM (kept for the tiny out GEMM, M=600): C = A @ W^T + bias
// ---------------------------------------------------------------------------
__global__ __launch_bounds__(256)
void gemm_nt_bias(const float* __restrict__ A, const float* __restrict__ W,
                  const float* __restrict__ bias, float* __restrict__ C, int M)
{
    __shared__ float As[32][68];
    __shared__ float Ws[32][68];
    const int tid = threadIdx.x;
    const int m0 = blockIdx.x * 64;
    const int n0 = blockIdx.y * 64;
    const int tx = tid & 15, ty = tid >> 4;
    float acc[4][4] = {};

    for (int k0 = 0; k0 < 256; k0 += 32) {
#pragma unroll
        for (int i = 0; i < 2; i++) {
            int t = tid + i * 256;
            int rr = t >> 3;
            int c4 = (t & 7) << 2;
            int ra = min(m0 + rr, M - 1);
            float4 va = *(const float4*)(A + (size_t)ra * 256 + k0 + c4);
            As[c4 + 0][rr] = va.x; As[c4 + 1][rr] = va.y;
            As[c4 + 2][rr] = va.z; As[c4 + 3][rr] = va.w;
            float4 vw = *(const float4*)(W + (size_t)(n0 + rr) * 256 + k0 + c4);
            Ws[c4 + 0][rr] = vw.x; Ws[c4 + 1][rr] = vw.y;
            Ws[c4 + 2][rr] = vw.z; Ws[c4 + 3][rr] = vw.w;
        }
        __syncthreads();
#pragma unroll
        for (int kk = 0; kk < 32; kk++) {
            float4 a = *(const float4*)&As[kk][ty * 4];
            float4 wv4 = *(const float4*)&Ws[kk][tx * 4];
            float av[4] = {a.x, a.y, a.z, a.w};
            float wv[4] = {wv4.x, wv4.y, wv4.z, wv4.w};
#pragma unroll
            for (int i = 0; i < 4; i++)
#pragma unroll
                for (int j = 0; j < 4; j++)
                    acc[i][j] += av[i] * wv[j];
        }
        __syncthreads();
    }
#pragma unroll
    for (int i = 0; i < 4; i++) {
        int rr = m0 + ty * 4 + i;
        if (rr >= M) continue;
        int n = n0 + tx * 4;
        float4 o;
        o.x = acc[i][0] + bias[n + 0];
        o.y = acc[i][1] + bias[n + 1];
        o.z = acc[i][2] + bias[n + 2];
        o.w = acc[i][3] + bias[n + 3];
        *(float4*)(C + (size_t)rr * 256 + n) = o;
    }
}

// ---------------------------------------------------------------------------
// Per-(b,q) parameter kernel: aw/ob GEMV + softmaxes + boxes -> params[bq*288]
// layout: [0:128) box[8][4] float4 | [128:256) wgt[8][4][4] | [256:288) cqd[8][4]
// ---------------------------------------------------------------------------
__global__ __launch_bounds__(256)
void param_kernel(const float* __restrict__ query,
                  const float* __restrict__ Wattn, const float* __restrict__ battn,
                  const float* __restrict__ Wbox,  const float* __restrict__ bbox,
                  const float* __restrict__ ref_windows,
                  const float* __restrict__ vvr,
                  float* __restrict__ params)
{
    __shared__ float qrow[256];
    __shared__ float awob[256];
    __shared__ float4 boxs[8][4];
    __shared__ float wgts[8][4][4];
    __shared__ float cqds[8][4];

    const int bq = blockIdx.x;
    const int b = bq / kQ;
    const int tid = threadIdx.x;

    if (tid < 64)
        ((float4*)qrow)[tid] = ((const float4*)(query + (size_t)bq * 256))[tid];
    __syncthreads();

    {
        const float* Wrow = (tid < 128) ? (Wattn + (size_t)tid * 256)
                                        : (Wbox + (size_t)(tid - 128) * 256);
        float s = (tid < 128) ? battn[tid] : bbox[tid - 128];
#pragma unroll 8
        for (int d4 = 0; d4 < 64; d4++) {
            float4 wv = ((const float4*)Wrow)[d4];
            float4 qv = ((const float4*)qrow)[d4];
            s += wv.x * qv.x + wv.y * qv.y + wv.z * qv.z + wv.w * qv.w;
        }
        awob[tid] = s;
    }
    __syncthreads();

    if (tid < 8) {
        const int h = tid;
        float m = -1e30f;
        float E[16];
#pragma unroll
        for (int i = 0; i < 16; i++) m = fmaxf(m, awob[h * 16 + i]);
        float Ssum = 0.f;
#pragma unroll
        for (int i = 0; i < 16; i++) { E[i] = expf(awob[h * 16 + i] - m); Ssum += E[i]; }
        float invS16 = 1.f / (16.f * Ssum);
#pragma unroll
        for (int qd = 0; qd < 4; qd++) {
            float Sq = E[qd] + E[4 + qd] + E[8 + qd] + E[12 + qd];
            float inv = 1.f / Sq;
#pragma unroll
            for (int l = 0; l < 4; l++) wgts[h][l][qd] = E[l * 4 + qd] * inv;
            cqds[h][qd] = Sq * invS16;
        }
    }
    if (tid >= 64 && tid < 96) {
        const int t = tid - 64;
        const int h = t >> 2, l = t & 3;
        float4 rw = ((const float4*)ref_windows)[bq];
        float ob0 = awob[128 + h * 16 + l * 4 + 0];
        float ob1 = awob[128 + h * 16 + l * 4 + 1];
        float ob2 = awob[128 + h * 16 + l * 4 + 2];
        float ob3 = awob[128 + h * 16 + l * 4 + 3];
        float cx = rw.x + ob0 * 0.125f * rw.z;
        float cy = rw.y + ob1 * 0.125f * rw.w;
        float sx = fmaxf(rw.z + ob2 * 0.125f * rw.z, 0.f);
        float sy = fmaxf(rw.w + ob3 * 0.125f * rw.w, 0.f);
        float vrx = vvr[(b * 4 + l) * 2 + 0];
        float vry = vvr[(b * 4 + l) * 2 + 1];
        boxs[h][l] = make_float4(cx * vrx, cy * vry, sx * vrx, sy * vry);
    }
    __syncthreads();

    float* p = params + (size_t)bq * 288;
    if (tid < 32)       ((float4*)p)[tid] = ((float4*)boxs)[tid];
    else if (tid < 64)  ((float4*)p)[tid] = ((float4*)wgts)[tid - 32];
    else if (tid < 72)  ((float4*)p)[tid] = ((float4*)cqds)[tid - 64];
}

// ---------------------------------------------------------------------------
// Sampler: grid 1200 = (bq, khalf); 256 threads = (hg 0..1, klocal 0..31, ch 0..3)
// tid = hg*128 + klocal*4 + ch.  Each thread: heads hg*4..+3, 16B bf16 chunk ch.
// Writes mask_pre (bf16) and out_part[blk][256] (f32, spatial partial).
// ---------------------------------------------------------------------------
__global__ __launch_bounds__(256)
void sample_bf16(const u16* __restrict__ valb,
                 const float* __restrict__ params,
                 u16* __restrict__ maskb,          // (B*Q*64, 256) bf16
                 float* __restrict__ out_part)     // (1200, 256)
{
    __shared__ float4 boxs[8][4];
    __shared__ float wgts[8][4][4];
    __shared__ float cqds[8][4];
    __shared__ float warr[4][4][32];

    const int blk = blockIdx.x;
    const int bq = blk >> 1;
    const int khalf = blk & 1;
    const int b = bq / kQ;
    const int tid = threadIdx.x;

    if (tid < 72) {
        float4 v = ((const float4*)(params + (size_t)bq * 288))[tid];
        if (tid < 32)      ((float4*)boxs)[tid] = v;
        else if (tid < 64) ((float4*)wgts)[tid - 32] = v;
        else               ((float4*)cqds)[tid - 64] = v;
    }
    __syncthreads();

    const int hg = tid >> 7;
    const int klocal = (tid >> 2) & 31;
    const int ch = tid & 3;
    const int k = khalf * 32 + klocal;
    const float kx = (float)(k & 7) * 0.125f - 0.4375f;
    const float ky = (float)(k >> 3) * 0.125f - 0.4375f;
    const int qd = (((k >> 5) & 1) << 1) | ((k >> 2) & 1);

    float acc[4][8];
#pragma unroll
    for (int hh = 0; hh < 4; hh++)
#pragma unroll
        for (int e = 0; e < 8; e++) acc[hh][e] = 0.f;

    static constexpr int LW[4]  = {128, 64, 32, 16};
    static constexpr int LST[4] = {0, 16384, 20480, 21504};

#pragma unroll
    for (int l = 0; l < 4; l++) {
        const int Wl = LW[l];
#pragma unroll
        for (int hh = 0; hh < 4; hh++) {
            const int h = hg * 4 + hh;
            const u16* vbase = valb + ((size_t)(b * kL2 + LST[l]) << 8) + h * 32 + ch * 8;
            float4 bx = boxs[h][l];
            float lw = wgts[h][l][qd];
            float x = (bx.x + kx * bx.z) * Wl - 0.5f;
            float y = (bx.y + ky * bx.w) * Wl - 0.5f;
            float x0f = floorf(x), y0f = floorf(y);
            float dx = x - x0f, dy = y - y0f;
            int x0 = (int)x0f, y0 = (int)y0f;
            int x1 = x0 + 1, y1 = y0 + 1;
            int x0c = min(max(x0, 0), Wl - 1), x1c = min(max(x1, 0), Wl - 1);
            int y0c = min(max(y0, 0), Wl - 1), y1c = min(max(y1, 0), Wl - 1);
            float vx0 = (x0 >= 0 && x0 < Wl) ? 1.f : 0.f;
            float vx1 = (x1 >= 0 && x1 < Wl) ? 1.f : 0.f;
            float vy0 = (y0 >= 0 && y0 < Wl) ? 1.f : 0.f;
            float vy1 = (y1 >= 0 && y1 < Wl) ? 1.f : 0.f;
            float w00 = (1.f - dx) * (1.f - dy) * vx0 * vy0 * lw;
            float w10 = dx * (1.f - dy) * vx1 * vy0 * lw;
            float w01 = (1.f - dx) * dy * vx0 * vy1 * lw;
            float w11 = dx * dy * vx1 * vy1 * lw;
            uint4 v00 = *(const uint4*)(vbase + ((size_t)(y0c * Wl + x0c) << 8));
            uint4 v10 = *(const uint4*)(vbase + ((size_t)(y0c * Wl + x1c) << 8));
            uint4 v01 = *(const uint4*)(vbase + ((size_t)(y1c * Wl + x0c) << 8));
            uint4 v11 = *(const uint4*)(vbase + ((size_t)(y1c * Wl + x1c) << 8));
            float* a = &acc[hh][0];
            a[0] += w00*lo16(v00.x) + w10*lo16(v10.x) + w01*lo16(v01.x) + w11*lo16(v11.x);
            a[1] += w00*hi16(v00.x) + w10*hi16(v10.x) + w01*hi16(v01.x) + w11*hi16(v11.x);
            a[2] += w00*lo16(v00.y) + w10*lo16(v10.y) + w01*lo16(v01.y) + w11*lo16(v11.y);
            a[3] += w00*hi16(v00.y) + w10*hi16(v10.y) + w01*hi16(v01.y) + w11*hi16(v11.y);
            a[4] += w00*lo16(v00.z) + w10*lo16(v10.z) + w01*lo16(v01.z) + w11*lo16(v11.z);
            a[5] += w00*hi16(v00.z) + w10*hi16(v10.z) + w01*hi16(v01.z) + w11*hi16(v11.z);
            a[6] += w00*lo16(v00.w) + w10*lo16(v10.w) + w01*lo16(v01.w) + w11*lo16(v11.w);
            a[7] += w00*hi16(v00.w) + w10*hi16(v10.w) + w01*hi16(v01.w) + w11*hi16(v11.w);
        }
    }

    // mask_pre bf16 write
#pragma unroll
    for (int hh = 0; hh < 4; hh++) {
        const int h = hg * 4 + hh;
        uint4 o;
        o.x = pack2(acc[hh][0], acc[hh][1]);
        o.y = pack2(acc[hh][2], acc[hh][3]);
        o.z = pack2(acc[hh][4], acc[hh][5]);
        o.w = pack2(acc[hh][6], acc[hh][7]);
        *(uint4*)(maskb + (((size_t)bq * 64 + k) << 8) + h * 32 + ch * 8) = o;
    }

    // spatial partial: c[h][qd(k)] * acc, reduced over klocal within wave
    const int lane = tid & 63;
    const int wv = tid >> 6;
#pragma unroll
    for (int hh = 0; hh < 4; hh++) {
        const int h = hg * 4 + hh;
        float c = cqds[h][qd];
#pragma unroll
        for (int e = 0; e < 8; e++) {
            float v = acc[hh][e] * c;
            v += __shfl_xor(v, 4);
            v += __shfl_xor(v, 8);
            v += __shfl_xor(v, 16);
            v += __shfl_xor(v, 32);
            if (lane < 4) warr[wv][hh][(lane & 3) * 8 + e] = v;
        }
    }
    __syncthreads();
    {
        int h = tid >> 5, e32 = tid & 31;
        float s = warr[(h >> 2) * 2][h & 3][e32] + warr[(h >> 2) * 2 + 1][h & 3][e32];
        out_part[(size_t)blk * 256 + tid] = s;
    }
}

// out_pre[bq] = out_part[2bq] + out_part[2bq+1]
__global__ __launch_bounds__(256)
void combine_kernel(const float* __restrict__ out_part, float* __restrict__ out_pre)
{
    const int bq = blockIdx.x;
    const int d = threadIdx.x;
    out_pre[(size_t)bq * 256 + d] = out_part[(size_t)(2 * bq) * 256 + d]
                                  + out_part[(size_t)(2 * bq + 1) * 256 + d];
}

// ---------------------------------------------------------------------------
extern "C" void kernel_launch(void* const* d_in, const int* in_sizes, int n_in,
                              void* d_out, int out_size, void* d_ws, size_t ws_size,
                              hipStream_t stream)
{
    const float* query       = (const float*)d_in[0];
    const float* value       = (const float*)d_in[1];
    const unsigned char* v_mask = (const unsigned char*)d_in[3];
    const float* vvr         = (const float*)d_in[5];
    const float* ref_windows = (const float*)d_in[6];
    const float* Wv    = (const float*)d_in[7];
    const float* bv    = (const float*)d_in[8];
    const float* Wbox  = (const float*)d_in[9];
    const float* bbox  = (const float*)d_in[10];
    const float* Wattn = (const float*)d_in[11];
    const float* battn = (const float*)d_in[12];
    const float* Wout  = (const float*)d_in[13];
    const float* bout  = (const float*)d_in[14];

    // workspace layout (bytes, all 16B aligned)
    char* wsp = (char*)d_ws;
    u16* value_b = (u16*)wsp;                 wsp += (size_t)11141120 * 2;  // 22.28MB
    u16* Wv_b    = (u16*)wsp;                 wsp += (size_t)65536 * 2;
    u16* Wout_b  = (u16*)wsp;                 wsp += (size_t)65536 * 2;
    u16* val_b   = (u16*)wsp;                 wsp += (size_t)11141120 * 2;  // 22.28MB
    u16* mask_b  = (u16*)wsp;                 wsp += (size_t)9830400 * 2;   // 19.66MB
    float* params   = (float*)wsp;            wsp += (size_t)600 * 288 * 4;
    float* out_part = (float*)wsp;            wsp += (size_t)1200 * 256 * 4;
    float* out_pre  = (float*)wsp;            wsp += (size_t)600 * 256 * 4;

    float* out  = (float*)d_out;              // 600*256
    float* mask = out + (size_t)600 * 256;    // 38400*256

    // 1) conversions to bf16
    f32_to_bf16<<<5440, 256, 0, stream>>>(value, value_b, 11141120);
    f32_to_bf16<<<32, 256, 0, stream>>>(Wv, Wv_b, 65536);
    f32_to_bf16<<<32, 256, 0, stream>>>(Wout, Wout_b, 65536);
    // 2) val = value @ Wv^T + bv (masked rows -> 0), bf16 out
    gemm_bf16<true><<<dim3(340, 2), 256, 0, stream>>>(value_b, Wv_b, bv, val_b, v_mask);
    // 3) per-query params
    param_kernel<<<600, 256, 0, stream>>>(query, Wattn, battn, Wbox, bbox,
                                          ref_windows, vvr, params);
    // 4) sampling -> mask_pre (bf16) + spatial partials
    sample_bf16<<<1200, 256, 0, stream>>>(val_b, params, mask_b, out_part);
    // 5) combine partials -> out_pre (f32)
    combine_kernel<<<600, 256, 0, stream>>>(out_part, out_pre);
    // 6) mask = mask_pre @ Wout^T + bout (f32 out)
    gemm_bf16<false><<<dim3(300, 2), 256, 0, stream>>>(mask_b, Wout_b, bout, mask, nullptr);
    // 7) out = out_pre @ Wout^T + bout (f32 GEMM, small)
    gemm_nt_bias<<<dim3(10, 4), 256, 0, stream>>>(out_pre, Wout, bout, out, 600);
}

// Round 5
// 138.652 us; speedup vs baseline: 2.8314x; 1.3002x over previous
//
#include <hip/hip_runtime.h>
#include <cstdint>
#include <cstddef>

typedef unsigned short u16;
typedef unsigned int   u32;
typedef __attribute__((ext_vector_type(8))) short bf16x8;
typedef __attribute__((ext_vector_type(4))) float f32x4;

static constexpr int kQ = 300;
static constexpr int kL2 = 21760;

__device__ __forceinline__ u16 bf16_rne(float f) {
    u32 u = __float_as_uint(f);
    u += 0x7FFFu + ((u >> 16) & 1u);
    return (u16)(u >> 16);
}
__device__ __forceinline__ u32 pack2(float lo, float hi) {
    return (u32)bf16_rne(lo) | ((u32)bf16_rne(hi) << 16);
}
__device__ __forceinline__ float lo16(u32 u) { return __uint_as_float(u << 16); }
__device__ __forceinline__ float hi16(u32 u) { return __uint_as_float(u & 0xFFFF0000u); }

// ---------------------------------------------------------------------------
// f32 -> bf16 (RNE), n divisible by 8
// ---------------------------------------------------------------------------
__global__ __launch_bounds__(256)
void f32_to_bf16(const float* __restrict__ src, u16* __restrict__ dst, int n)
{
    int i = (blockIdx.x * 256 + threadIdx.x) * 8;
    if (i >= n) return;
    float4 a = *(const float4*)(src + i);
    float4 b = *(const float4*)(src + i + 4);
    uint4 o;
    o.x = pack2(a.x, a.y); o.y = pack2(a.z, a.w);
    o.z = pack2(b.x, b.y); o.w = pack2(b.z, b.w);
    *(uint4*)(dst + i) = o;
}

// ---------------------------------------------------------------------------
// MFMA bf16 GEMM: C[M,256] = A[M,256] @ W[256,256]^T + bias, opt rowmask.
// BM=BN=128, BK=32, 256 threads (4 waves, 2x2), wave tile 64x64 (4x4 frags).
// M must be divisible by 128. OUT_BF16: LDS-bounce epilogue, bf16 output.
// ---------------------------------------------------------------------------
template<bool OUT_BF16>
__global__ __launch_bounds__(256)
void gemm_bf16(const u16* __restrict__ A, const u16* __restrict__ W,
               const float* __restrict__ bias, void* __restrict__ Cout,
               const unsigned char* __restrict__ rowmask)
{
    __shared__ u16 S[8192];            // 16KB: As=S[0:4096), Bs=S[4096:8192)
    u16* As = S;
    u16* Bs = S + 4096;
    const int tid = threadIdx.x;
    const int m0 = blockIdx.x * 128;
    const int n0 = blockIdx.y * 128;
    const int lane = tid & 63;
    const int w = tid >> 6;
    const int wm = w & 1, wn = w >> 1;
    const int g = lane >> 4, r = lane & 15;

    f32x4 acc[4][4];
#pragma unroll
    for (int i = 0; i < 4; i++)
#pragma unroll
        for (int j = 0; j < 4; j++)
            acc[i][j] = (f32x4){0.f, 0.f, 0.f, 0.f};

    for (int kt = 0; kt < 8; ++kt) {
        const int k0 = kt * 32;
#pragma unroll
        for (int i = 0; i < 2; ++i) {
            int c = tid + i * 256;          // 0..511
            int m = c >> 2, gg = c & 3;
            uint4 va = *(const uint4*)(A + (size_t)(m0 + m) * 256 + k0 + gg * 8);
            *(uint4*)(As + ((gg * 128 + m) << 3)) = va;
            uint4 vb = *(const uint4*)(W + (size_t)(n0 + m) * 256 + k0 + gg * 8);
            *(uint4*)(Bs + ((gg * 128 + m) << 3)) = vb;
        }
        __syncthreads();
        bf16x8 af[4], bf[4];
#pragma unroll
        for (int mf = 0; mf < 4; ++mf)
            af[mf] = *(const bf16x8*)(As + ((g * 128 + wm * 64 + mf * 16 + r) << 3));
#pragma unroll
        for (int nf = 0; nf < 4; ++nf)
            bf[nf] = *(const bf16x8*)(Bs + ((g * 128 + wn * 64 + nf * 16 + r) << 3));
#pragma unroll
        for (int mf = 0; mf < 4; ++mf)
#pragma unroll
            for (int nf = 0; nf < 4; ++nf)
                acc[mf][nf] = __builtin_amdgcn_mfma_f32_16x16x32_bf16(
                    af[mf], bf[nf], acc[mf][nf], 0, 0, 0);
        __syncthreads();
    }

    if (!OUT_BF16) {
        float* C = (float*)Cout;
#pragma unroll
        for (int nf = 0; nf < 4; ++nf) {
            int ng = n0 + wn * 64 + nf * 16 + r;
            float bb = bias[ng];
#pragma unroll
            for (int mf = 0; mf < 4; ++mf) {
                int mg = m0 + wm * 64 + mf * 16 + g * 4;
#pragma unroll
                for (int reg = 0; reg < 4; ++reg) {
                    float z = 1.f;
                    if (rowmask && rowmask[mg + reg]) z = 0.f;
                    C[(size_t)(mg + reg) * 256 + ng] = (acc[mf][nf][reg] + bb) * z;
                }
            }
        }
    } else {
        u16* C = (u16*)Cout;
#pragma unroll
        for (int round = 0; round < 2; ++round) {
            __syncthreads();
            if (wn == round) {
#pragma unroll
                for (int nf = 0; nf < 4; ++nf) {
                    int col = nf * 16 + r;
                    float bb = bias[n0 + round * 64 + col];
#pragma unroll
                    for (int mf = 0; mf < 4; ++mf) {
                        int row0 = wm * 64 + mf * 16 + g * 4;
#pragma unroll
                        for (int reg = 0; reg < 4; ++reg) {
                            float z = 1.f;
                            if (rowmask && rowmask[m0 + row0 + reg]) z = 0.f;
                            S[(row0 + reg) * 64 + col] =
                                bf16_rne((acc[mf][nf][reg] + bb) * z);
                        }
                    }
                }
            }
            __syncthreads();
            int row = tid >> 1, hb = tid & 1;
            const u16* src = S + row * 64 + hb * 32;
            u16* dst = C + (size_t)(m0 + row) * 256 + n0 + round * 64 + hb * 32;
#pragma unroll
            for (int j = 0; j < 4; ++j)
                ((uint4*)dst)[j] = ((const uint4*)src)[j];
        }
    }
}

// ---------------------------------------------------------------------------
// f32 GEMM (kept for the tiny out GEMM, M=600): C = A @ W^T + bias
// ---------------------------------------------------------------------------
__global__ __launch_bounds__(256)
void gemm_nt_bias(const float* __restrict__ A, const float* __restrict__ W,
                  const float* __restrict__ bias, float* __restrict__ C, int M)
{
    __shared__ float As[32][68];
    __shared__ float Ws[32][68];
    const int tid = threadIdx.x;
    const int m0 = blockIdx.x * 64;
    const int n0 = blockIdx.y * 64;
    const int tx = tid & 15, ty = tid >> 4;
    float acc[4][4] = {};

    for (int k0 = 0; k0 < 256; k0 += 32) {
#pragma unroll
        for (int i = 0; i < 2; i++) {
            int t = tid + i * 256;
            int rr = t >> 3;
            int c4 = (t & 7) << 2;
            int ra = min(m0 + rr, M - 1);
            float4 va = *(const float4*)(A + (size_t)ra * 256 + k0 + c4);
            As[c4 + 0][rr] = va.x; As[c4 + 1][rr] = va.y;
            As[c4 + 2][rr] = va.z; As[c4 + 3][rr] = va.w;
            float4 vw = *(const float4*)(W + (size_t)(n0 + rr) * 256 + k0 + c4);
            Ws[c4 + 0][rr] = vw.x; Ws[c4 + 1][rr] = vw.y;
            Ws[c4 + 2][rr] = vw.z; Ws[c4 + 3][rr] = vw.w;
        }
        __syncthreads();
#pragma unroll
        for (int kk = 0; kk < 32; kk++) {
            float4 a = *(const float4*)&As[kk][ty * 4];
            float4 wv4 = *(const float4*)&Ws[kk][tx * 4];
            float av[4] = {a.x, a.y, a.z, a.w};
            float wv[4] = {wv4.x, wv4.y, wv4.z, wv4.w};
#pragma unroll
            for (int i = 0; i < 4; i++)
#pragma unroll
                for (int j = 0; j < 4; j++)
                    acc[i][j] += av[i] * wv[j];
        }
        __syncthreads();
    }
#pragma unroll
    for (int i = 0; i < 4; i++) {
        int rr = m0 + ty * 4 + i;
        if (rr >= M) continue;
        int n = n0 + tx * 4;
        float4 o;
        o.x = acc[i][0] + bias[n + 0];
        o.y = acc[i][1] + bias[n + 1];
        o.z = acc[i][2] + bias[n + 2];
        o.w = acc[i][3] + bias[n + 3];
        *(float4*)(C + (size_t)rr * 256 + n) = o;
    }
}

// ---------------------------------------------------------------------------
// Per-(b,q) parameter kernel: aw/ob GEMV + softmaxes + boxes -> params[bq*288]
// layout: [0:128) box[8][4] float4 | [128:256) wgt[8][4][4] | [256:288) cqd[8][4]
// ---------------------------------------------------------------------------
__global__ __launch_bounds__(256)
void param_kernel(const float* __restrict__ query,
                  const float* __restrict__ Wattn, const float* __restrict__ battn,
                  const float* __restrict__ Wbox,  const float* __restrict__ bbox,
                  const float* __restrict__ ref_windows,
                  const float* __restrict__ vvr,
                  float* __restrict__ params)
{
    __shared__ float qrow[256];
    __shared__ float awob[256];
    __shared__ float4 boxs[8][4];
    __shared__ float wgts[8][4][4];
    __shared__ float cqds[8][4];

    const int bq = blockIdx.x;
    const int b = bq / kQ;
    const int tid = threadIdx.x;

    if (tid < 64)
        ((float4*)qrow)[tid] = ((const float4*)(query + (size_t)bq * 256))[tid];
    __syncthreads();

    {
        const float* Wrow = (tid < 128) ? (Wattn + (size_t)tid * 256)
                                        : (Wbox + (size_t)(tid - 128) * 256);
        float s = (tid < 128) ? battn[tid] : bbox[tid - 128];
#pragma unroll 8
        for (int d4 = 0; d4 < 64; d4++) {
            float4 wv = ((const float4*)Wrow)[d4];
            float4 qv = ((const float4*)qrow)[d4];
            s += wv.x * qv.x + wv.y * qv.y + wv.z * qv.z + wv.w * qv.w;
        }
        awob[tid] = s;
    }
    __syncthreads();

    if (tid < 8) {
        const int h = tid;
        float m = -1e30f;
        float E[16];
#pragma unroll
        for (int i = 0; i < 16; i++) m = fmaxf(m, awob[h * 16 + i]);
        float Ssum = 0.f;
#pragma unroll
        for (int i = 0; i < 16; i++) { E[i] = expf(awob[h * 16 + i] - m); Ssum += E[i]; }
        float invS16 = 1.f / (16.f * Ssum);
#pragma unroll
        for (int qd = 0; qd < 4; qd++) {
            float Sq = E[qd] + E[4 + qd] + E[8 + qd] + E[12 + qd];
            float inv = 1.f / Sq;
#pragma unroll
            for (int l = 0; l < 4; l++) wgts[h][l][qd] = E[l * 4 + qd] * inv;
            cqds[h][qd] = Sq * invS16;
        }
    }
    if (tid >= 64 && tid < 96) {
        const int t = tid - 64;
        const int h = t >> 2, l = t & 3;
        float4 rw = ((const float4*)ref_windows)[bq];
        float ob0 = awob[128 + h * 16 + l * 4 + 0];
        float ob1 = awob[128 + h * 16 + l * 4 + 1];
        float ob2 = awob[128 + h * 16 + l * 4 + 2];
        float ob3 = awob[128 + h * 16 + l * 4 + 3];
        float cx = rw.x + ob0 * 0.125f * rw.z;
        float cy = rw.y + ob1 * 0.125f * rw.w;
        float sx = fmaxf(rw.z + ob2 * 0.125f * rw.z, 0.f);
        float sy = fmaxf(rw.w + ob3 * 0.125f * rw.w, 0.f);
        float vrx = vvr[(b * 4 + l) * 2 + 0];
        float vry = vvr[(b * 4 + l) * 2 + 1];
        boxs[h][l] = make_float4(cx * vrx, cy * vry, sx * vrx, sy * vry);
    }
    __syncthreads();

    float* p = params + (size_t)bq * 288;
    if (tid < 32)       ((float4*)p)[tid] = ((float4*)boxs)[tid];
    else if (tid < 64)  ((float4*)p)[tid] = ((float4*)wgts)[tid - 32];
    else if (tid < 72)  ((float4*)p)[tid] = ((float4*)cqds)[tid - 64];
}

// ---------------------------------------------------------------------------
// Sampler: grid 2400 = (bq, kquarter); 512 threads = (klocal 0..15, h 0..7, ch 0..3)
// One head per thread -> acc[8] only (low VGPR, high occupancy).
// Writes mask_pre (bf16) and out_part[blk][256] (f32, spatial partial).
// ---------------------------------------------------------------------------
__global__ __launch_bounds__(512)
void sample_bf16(const u16* __restrict__ valb,
                 const float* __restrict__ params,
                 u16* __restrict__ maskb,          // (B*Q*64, 256) bf16
                 float* __restrict__ out_part)     // (2400, 256)
{
    __shared__ float4 boxs[8][4];
    __shared__ float wgts[8][4][4];
    __shared__ float cqds[8][4];
    __shared__ float warr[8][256];

    const int blk = blockIdx.x;
    const int bq = blk >> 2;
    const int kq = blk & 3;
    const int b = bq / kQ;
    const int tid = threadIdx.x;

    if (tid < 72) {
        float4 v = ((const float4*)(params + (size_t)bq * 288))[tid];
        if (tid < 32)      ((float4*)boxs)[tid] = v;
        else if (tid < 64) ((float4*)wgts)[tid - 32] = v;
        else               ((float4*)cqds)[tid - 64] = v;
    }
    __syncthreads();

    const int klocal = tid >> 5;            // 0..15
    const int h = (tid >> 2) & 7;           // 0..7
    const int ch = tid & 3;                 // 0..3
    const int k = kq * 16 + klocal;
    const float kx = (float)(k & 7) * 0.125f - 0.4375f;
    const float ky = (float)(k >> 3) * 0.125f - 0.4375f;
    const int qd = (((k >> 5) & 1) << 1) | ((k >> 2) & 1);

    float acc[8];
#pragma unroll
    for (int e = 0; e < 8; e++) acc[e] = 0.f;

    static constexpr int LW[4]  = {128, 64, 32, 16};
    static constexpr int LST[4] = {0, 16384, 20480, 21504};

#pragma unroll
    for (int l = 0; l < 4; l++) {
        const int Wl = LW[l];
        const u16* vbase = valb + ((size_t)(b * kL2 + LST[l]) << 8) + h * 32 + ch * 8;
        float4 bx = boxs[h][l];
        float lw = wgts[h][l][qd];
        float x = (bx.x + kx * bx.z) * Wl - 0.5f;
        float y = (bx.y + ky * bx.w) * Wl - 0.5f;
        float x0f = floorf(x), y0f = floorf(y);
        float dx = x - x0f, dy = y - y0f;
        int x0 = (int)x0f, y0 = (int)y0f;
        int x1 = x0 + 1, y1 = y0 + 1;
        int x0c = min(max(x0, 0), Wl - 1), x1c = min(max(x1, 0), Wl - 1);
        int y0c = min(max(y0, 0), Wl - 1), y1c = min(max(y1, 0), Wl - 1);
        float vx0 = (x0 >= 0 && x0 < Wl) ? 1.f : 0.f;
        float vx1 = (x1 >= 0 && x1 < Wl) ? 1.f : 0.f;
        float vy0 = (y0 >= 0 && y0 < Wl) ? 1.f : 0.f;
        float vy1 = (y1 >= 0 && y1 < Wl) ? 1.f : 0.f;
        float w00 = (1.f - dx) * (1.f - dy) * vx0 * vy0 * lw;
        float w10 = dx * (1.f - dy) * vx1 * vy0 * lw;
        float w01 = (1.f - dx) * dy * vx0 * vy1 * lw;
        float w11 = dx * dy * vx1 * vy1 * lw;
        uint4 v00 = *(const uint4*)(vbase + ((size_t)(y0c * Wl + x0c) << 8));
        uint4 v10 = *(const uint4*)(vbase + ((size_t)(y0c * Wl + x1c) << 8));
        uint4 v01 = *(const uint4*)(vbase + ((size_t)(y1c * Wl + x0c) << 8));
        uint4 v11 = *(const uint4*)(vbase + ((size_t)(y1c * Wl + x1c) << 8));
        acc[0] += w00*lo16(v00.x) + w10*lo16(v10.x) + w01*lo16(v01.x) + w11*lo16(v11.x);
        acc[1] += w00*hi16(v00.x) + w10*hi16(v10.x) + w01*hi16(v01.x) + w11*hi16(v11.x);
        acc[2] += w00*lo16(v00.y) + w10*lo16(v10.y) + w01*lo16(v01.y) + w11*lo16(v11.y);
        acc[3] += w00*hi16(v00.y) + w10*hi16(v10.y) + w01*hi16(v01.y) + w11*hi16(v11.y);
        acc[4] += w00*lo16(v00.z) + w10*lo16(v10.z) + w01*lo16(v01.z) + w11*lo16(v11.z);
        acc[5] += w00*hi16(v00.z) + w10*hi16(v10.z) + w01*hi16(v01.z) + w11*hi16(v11.z);
        acc[6] += w00*lo16(v00.w) + w10*lo16(v10.w) + w01*lo16(v01.w) + w11*lo16(v11.w);
        acc[7] += w00*hi16(v00.w) + w10*hi16(v10.w) + w01*hi16(v01.w) + w11*hi16(v11.w);
    }

    // mask_pre bf16 write (32 consecutive lanes cover one full 512B row)
    {
        uint4 o;
        o.x = pack2(acc[0], acc[1]);
        o.y = pack2(acc[2], acc[3]);
        o.z = pack2(acc[4], acc[5]);
        o.w = pack2(acc[6], acc[7]);
        *(uint4*)(maskb + (((size_t)bq * 64 + k) << 8) + h * 32 + ch * 8) = o;
    }

    // spatial partial: c[h][qd(k)] * acc, reduce over klocal
    {
        const int wave = tid >> 6;
        const int lane = tid & 63;
        float c = cqds[h][qd];
#pragma unroll
        for (int e = 0; e < 8; e++) {
            float v = acc[e] * c;
            v += __shfl_xor(v, 32);     // combine the wave's two klocal values
            if (lane < 32) warr[wave][h * 32 + ch * 8 + e] = v;
        }
    }
    __syncthreads();
    if (tid < 256) {
        float s = 0.f;
#pragma unroll
        for (int wv = 0; wv < 8; wv++) s += warr[wv][tid];
        out_part[(size_t)blk * 256 + tid] = s;
    }
}

// out_pre[bq] = sum of 4 block partials (deterministic)
__global__ __launch_bounds__(256)
void combine_kernel(const float* __restrict__ out_part, float* __restrict__ out_pre)
{
    const int bq = blockIdx.x;
    const int d = threadIdx.x;
    const float* p = out_part + (size_t)(4 * bq) * 256 + d;
    out_pre[(size_t)bq * 256 + d] = (p[0] + p[256]) + (p[512] + p[768]);
}

// ---------------------------------------------------------------------------
extern "C" void kernel_launch(void* const* d_in, const int* in_sizes, int n_in,
                              void* d_out, int out_size, void* d_ws, size_t ws_size,
                              hipStream_t stream)
{
    const float* query       = (const float*)d_in[0];
    const float* value       = (const float*)d_in[1];
    const unsigned char* v_mask = (const unsigned char*)d_in[3];
    const float* vvr         = (const float*)d_in[5];
    const float* ref_windows = (const float*)d_in[6];
    const float* Wv    = (const float*)d_in[7];
    const float* bv    = (const float*)d_in[8];
    const float* Wbox  = (const float*)d_in[9];
    const float* bbox  = (const float*)d_in[10];
    const float* Wattn = (const float*)d_in[11];
    const float* battn = (const float*)d_in[12];
    const float* Wout  = (const float*)d_in[13];
    const float* bout  = (const float*)d_in[14];

    // workspace layout (bytes, all 16B aligned)
    char* wsp = (char*)d_ws;
    u16* value_b = (u16*)wsp;                 wsp += (size_t)11141120 * 2;
    u16* Wv_b    = (u16*)wsp;                 wsp += (size_t)65536 * 2;
    u16* Wout_b  = (u16*)wsp;                 wsp += (size_t)65536 * 2;
    u16* val_b   = (u16*)wsp;                 wsp += (size_t)11141120 * 2;
    u16* mask_b  = (u16*)wsp;                 wsp += (size_t)9830400 * 2;
    float* params   = (float*)wsp;            wsp += (size_t)600 * 288 * 4;
    float* out_part = (float*)wsp;            wsp += (size_t)2400 * 256 * 4;
    float* out_pre  = (float*)wsp;            wsp += (size_t)600 * 256 * 4;

    float* out  = (float*)d_out;              // 600*256
    float* mask = out + (size_t)600 * 256;    // 38400*256

    // 1) conversions to bf16
    f32_to_bf16<<<5440, 256, 0, stream>>>(value, value_b, 11141120);
    f32_to_bf16<<<32, 256, 0, stream>>>(Wv, Wv_b, 65536);
    f32_to_bf16<<<32, 256, 0, stream>>>(Wout, Wout_b, 65536);
    // 2) val = value @ Wv^T + bv (masked rows -> 0), bf16 out
    gemm_bf16<true><<<dim3(340, 2), 256, 0, stream>>>(value_b, Wv_b, bv, val_b, v_mask);
    // 3) per-query params
    param_kernel<<<600, 256, 0, stream>>>(query, Wattn, battn, Wbox, bbox,
                                          ref_windows, vvr, params);
    // 4) sampling -> mask_pre (bf16) + spatial partials
    sample_bf16<<<2400, 512, 0, stream>>>(val_b, params, mask_b, out_part);
    // 5) combine partials -> out_pre (f32)
    combine_kernel<<<600, 256, 0, stream>>>(out_part, out_pre);
    // 6) mask = mask_pre @ Wout^T + bout (f32 out)
    gemm_bf16<false><<<dim3(300, 2), 256, 0, stream>>>(mask_b, Wout_b, bout, mask, nullptr);
    // 7) out = out_pre @ Wout^T + bout (f32 GEMM, small)
    gemm_nt_bias<<<dim3(10, 4), 256, 0, stream>>>(out_pre, Wout, bout, out, 600);
}